// Round 21
// baseline (67.831 us; speedup 1.0000x reference)
//
#include <hip/hip_runtime.h>

#define EMB_STRIDE 393216  // 96*64*64 elements per sample

typedef __attribute__((ext_vector_type(8))) short short8;
typedef __attribute__((ext_vector_type(4))) float f32x4;
typedef __attribute__((ext_vector_type(2))) __fp16 f16x2;

#define MFMA16 __builtin_amdgcn_mfma_f32_16x16x32_bf16
#define SCHED_PIN() __builtin_amdgcn_sched_barrier(0)

static __device__ __forceinline__ short bf16h(float v) {
    unsigned u = __builtin_bit_cast(unsigned, v);
    unsigned r = (u + 0x7FFFu + ((u >> 16) & 1u)) >> 16;
    return (short)r;
}
static __device__ __forceinline__ float bf16f(short s) {
    unsigned u = ((unsigned)(unsigned short)s) << 16;
    return __builtin_bit_cast(float, u);
}
// pack value as (hi_bf16 << 16) | lo_bf16 where v ~= hi + lo (lo truncated)
static __device__ __forceinline__ unsigned packsplit(float v) {
    const short h = bf16h(v);
    const float d = v - bf16f(h);
    const unsigned lo = __builtin_bit_cast(unsigned, d) >> 16;
    return ((unsigned)(unsigned short)h << 16) | lo;
}

// ---------------- Kernel 1: patch merge (RAW reshape) + 48->96 linear as MFMA.
// Blocks 0..1023: main patch GEMM, lin_w A-frags loaded INLINE (L2-resident).
// Blocks 1024..1087: pack in_proj/out_proj into MFMA A-frag hi/lo planes for
// k_msa (64-way parallel; consumed only by the NEXT kernel -> no race).
__global__ __launch_bounds__(256, 3) void k_patch(
    const float* __restrict__ x, const float* __restrict__ lin_w,
    const float* __restrict__ lin_b, const float* __restrict__ in_w,
    const float* __restrict__ out_w, unsigned* __restrict__ embp,
    short* __restrict__ WH, short* __restrict__ WL2,
    short* __restrict__ WOH, short* __restrict__ WOL) {
    const int bid = blockIdx.x;
    const int tid = threadIdx.x;

    if (bid >= 1024) {
        const int i0 = (bid - 1024) * 256 + tid;
        const int stride = 64 * 256;
        for (int i = i0; i < 27648; i += stride) {
            int j = i & 7, g = (i >> 3) & 3, rest = i >> 5;
            int f = rest % 288, kc = rest / 288;
            float v = in_w[f * 96 + kc * 32 + g * 8 + j];
            short h = bf16h(v);
            WH[i] = h; WL2[i] = bf16h(v - bf16f(h));
        }
        for (int i = i0; i < 9216; i += stride) {
            int j = i & 7, g = (i >> 3) & 3, rest = i >> 5;
            int f = rest % 96, kc = rest / 96;
            float v = out_w[f * 96 + kc * 32 + g * 8 + j];
            short h = bf16h(v);
            WOH[i] = h; WOL[i] = bf16h(v - bf16f(h));
        }
        return;
    }

    const int wave = tid >> 6, lane = tid & 63;
    const int n = bid >> 6;
    const int T = (bid & 63) * 4 + wave;   // 0..255
    const int a = T >> 6, b = (T >> 2) & 15, cc = T & 3;
    const int col16 = lane & 15, grp = lane >> 4;
    const int d = col16 >> 2, g = col16 & 3;

    const int rowoff = (a * 4 + d) * 256 + b * 16 + cc * 4 + g;
    const int gA = (grp >> 1) * 65536 + (grp & 1) * 32768;
    const float* p0 = x + (size_t)n * 196608 + rowoff + gA;

    // ---- B-frags: per-lane gather + bf16 hi/lo split
    float v0[8], v1[8];
#pragma unroll
    for (int j = 0; j < 8; ++j) v0[j] = p0[j * 4096];
    if (grp < 2) {
#pragma unroll
        for (int j = 0; j < 8; ++j) v1[j] = p0[131072 - (grp >> 1) * 65536 + j * 4096];
    }
    SCHED_PIN();
    short8 Bh[2], Bl[2];
#pragma unroll
    for (int j = 0; j < 8; ++j) {
        const short h = bf16h(v0[j]);
        Bh[0][j] = h; Bl[0][j] = bf16h(v0[j] - bf16f(h));
        Bh[1][j] = 0; Bl[1][j] = 0;
    }
    if (grp < 2) {
#pragma unroll
        for (int j = 0; j < 8; ++j) {
            const short h = bf16h(v1[j]);
            Bh[1][j] = h; Bl[1][j] = bf16h(v1[j] - bf16f(h));
        }
    }

    // ---- 6 e-tiles x (2 kc x 3 splits) MFMA; A-frags loaded inline from lin_w.
    f32x4 acc[6];
#pragma unroll
    for (int et = 0; et < 6; ++et) acc[et] = (f32x4){0.f, 0.f, 0.f, 0.f};
#pragma unroll
    for (int kc = 0; kc < 2; ++kc) {
        float wv[6][8];
        const bool valid = (kc == 0) | (grp < 2);
#pragma unroll
        for (int et = 0; et < 6; ++et) {
            const float* wr = lin_w + (et * 16 + col16) * 48 + kc * 32 + grp * 8;
            const float4 wa = valid ? *(const float4*)(wr)     : make_float4(0.f, 0.f, 0.f, 0.f);
            const float4 wb = valid ? *(const float4*)(wr + 4) : make_float4(0.f, 0.f, 0.f, 0.f);
            wv[et][0] = wa.x; wv[et][1] = wa.y; wv[et][2] = wa.z; wv[et][3] = wa.w;
            wv[et][4] = wb.x; wv[et][5] = wb.y; wv[et][6] = wb.z; wv[et][7] = wb.w;
        }
        SCHED_PIN();
        short8 AH[6], AL[6];
#pragma unroll
        for (int et = 0; et < 6; ++et)
#pragma unroll
            for (int j = 0; j < 8; ++j) {
                const short h = bf16h(wv[et][j]);
                AH[et][j] = h;
                AL[et][j] = bf16h(wv[et][j] - bf16f(h));
            }
#pragma unroll
        for (int et = 0; et < 6; ++et) acc[et] = MFMA16(AH[et], Bh[kc], acc[et], 0, 0, 0);
#pragma unroll
        for (int et = 0; et < 6; ++et) acc[et] = MFMA16(AH[et], Bl[kc], acc[et], 0, 0, 0);
#pragma unroll
        for (int et = 0; et < 6; ++et) acc[et] = MFMA16(AL[et], Bh[kc], acc[et], 0, 0, 0);
    }

    // ---- bias + packed store: e = et*16 + grp*4 + r, o = T*16 + col16
    unsigned* ebase = embp + (size_t)n * EMB_STRIDE + T * 16 + col16;
#pragma unroll
    for (int et = 0; et < 6; ++et) {
        const float4 bv = *(const float4*)(lin_b + et * 16 + grp * 4);
        const float vr[4] = {acc[et][0] + bv.x, acc[et][1] + bv.y,
                             acc[et][2] + bv.z, acc[et][3] + bv.w};
#pragma unroll
        for (int r = 0; r < 4; ++r)
            ebase[(size_t)(et * 16 + grp * 4 + r) * 4096] = packsplit(vr[r]);
    }
}

// ---------------- Kernel 2: fused window-MSA.
// r20 structure, but the softmax phase is a ROLLED 24-iteration loop (code-size
// cut ~20x for that phase): per-head q (pre-scaled by log2e) and packed (k,v)
// fp16 pairs live in LDS; each iteration reads its own row (4 broadcast b128 +
// 1 b32), computes, and writes AO over the same row (disjoint rows; lockstep).
__global__ __launch_bounds__(128, 2) void k_msa(
    const unsigned* __restrict__ embp,
    const short* __restrict__ WH, const short* __restrict__ WL2,
    const short* __restrict__ WOH, const short* __restrict__ WOL,
    const float* __restrict__ in_b, const float* __restrict__ out_b,
    float* __restrict__ out) {

    __shared__ unsigned KVf[2 * 96 * 20];  // per-window KV then AO, [h][n] stride 20
    __shared__ float    QS [2 * 96 * 17];  // per-window q*log2e, [h][n] stride 17

    const int tid = threadIdx.x;
    const int half = tid >> 6, lane = tid & 63;
    const int wl0 = blockIdx.x * 2;
    const int n = lane & 15, g = lane >> 4;
    const int hoff = half * 1536;

    // ---- B-frags (X^T) for BOTH windows: 12 uint4 loads in flight
    uint4 ub[12];
#pragma unroll
    for (int w = 0; w < 2; ++w) {
        const unsigned* xrow = embp + (size_t)n * EMB_STRIDE + (wl0 + w) * 96;
#pragma unroll
        for (int kc = 0; kc < 3; ++kc) {
            ub[(w * 3 + kc) * 2]     = *(const uint4*)(xrow + kc * 32 + g * 8);
            ub[(w * 3 + kc) * 2 + 1] = *(const uint4*)(xrow + kc * 32 + g * 8 + 4);
        }
    }
    SCHED_PIN();
    short8 Bh[2][3], Bl[2][3];
#pragma unroll
    for (int w = 0; w < 2; ++w)
#pragma unroll
        for (int kc = 0; kc < 3; ++kc) {
            const uint4 ua0 = ub[(w * 3 + kc) * 2], ua1 = ub[(w * 3 + kc) * 2 + 1];
            const unsigned ua[8] = {ua0.x, ua0.y, ua0.z, ua0.w, ua1.x, ua1.y, ua1.z, ua1.w};
#pragma unroll
            for (int j = 0; j < 8; ++j) {
                Bh[w][kc][j] = (short)(ua[j] >> 16);
                Bl[w][kc][j] = (short)(ua[j] & 0xffffu);
            }
        }

    // ---- QKV: 9 f-tiles per half, K=96, bf16x2, 2 windows
    f32x4 acc0[9], acc1[9];
#pragma unroll
    for (int a = 0; a < 9; ++a) {
        acc0[a] = (f32x4){0.f, 0.f, 0.f, 0.f};
        acc1[a] = (f32x4){0.f, 0.f, 0.f, 0.f};
    }
#pragma unroll
    for (int kc = 0; kc < 3; ++kc) {
        const short* whp = WH  + kc * 9216 + n * 32 + g * 8 + hoff;
        const short* wlp = WL2 + kc * 9216 + n * 32 + g * 8 + hoff;
        short8 AH[9], AL[9];
#pragma unroll
        for (int a = 0; a < 9; ++a)
            AH[a] = *(const short8*)(whp + ((a / 3) * 6 + (a % 3)) * 512);
#pragma unroll
        for (int a = 0; a < 9; ++a)
            AL[a] = *(const short8*)(wlp + ((a / 3) * 6 + (a % 3)) * 512);
        SCHED_PIN();
#pragma unroll
        for (int a = 0; a < 9; ++a) acc0[a] = MFMA16(AH[a], Bh[0][kc], acc0[a], 0, 0, 0);
#pragma unroll
        for (int a = 0; a < 9; ++a) acc1[a] = MFMA16(AH[a], Bh[1][kc], acc1[a], 0, 0, 0);
#pragma unroll
        for (int a = 0; a < 9; ++a) acc0[a] = MFMA16(AH[a], Bl[0][kc], acc0[a], 0, 0, 0);
#pragma unroll
        for (int a = 0; a < 9; ++a) acc1[a] = MFMA16(AH[a], Bl[1][kc], acc1[a], 0, 0, 0);
#pragma unroll
        for (int a = 0; a < 9; ++a) acc0[a] = MFMA16(AL[a], Bh[0][kc], acc0[a], 0, 0, 0);
#pragma unroll
        for (int a = 0; a < 9; ++a) acc1[a] = MFMA16(AL[a], Bh[1][kc], acc1[a], 0, 0, 0);
    }
#pragma unroll
    for (int a = 0; a < 9; ++a) {
        const float4 bv = *(const float4*)(in_b + ((a / 3) * 6 + (a % 3)) * 16 + half * 48 + g * 4);
        acc0[a][0] += bv.x; acc0[a][1] += bv.y; acc0[a][2] += bv.z; acc0[a][3] += bv.w;
        acc1[a][0] += bv.x; acc1[a][1] += bv.y; acc1[a][2] += bv.z; acc1[a][3] += bv.w;
    }

    // ---- phase A: stage q (pre-scaled) and packed (k,v) pairs to LDS
#pragma unroll
    for (int c = 0; c < 3; ++c)
#pragma unroll
        for (int r2 = 0; r2 < 4; ++r2) {
            const int h = half * 48 + c * 16 + g * 4 + r2;
            QS[h * 17 + n]        = acc0[c][r2] * 1.44269504f;
            QS[1632 + h * 17 + n] = acc1[c][r2] * 1.44269504f;
            const f16x2 p0 = __builtin_amdgcn_cvt_pkrtz(acc0[3 + c][r2], acc0[6 + c][r2]);
            const f16x2 p1 = __builtin_amdgcn_cvt_pkrtz(acc1[3 + c][r2], acc1[6 + c][r2]);
            KVf[h * 20 + n]        = __builtin_bit_cast(unsigned, p0);
            KVf[1920 + h * 20 + n] = __builtin_bit_cast(unsigned, p1);
        }

    // ---- phase B: ROLLED softmax loop (24 bodies; h = c*16 + g*4 + r2 per half)
#pragma clang loop unroll(disable)
    for (int it = 0; it < 24; ++it) {
        const int W = it & 1;
        const int idx = it >> 1;
        const int h = half * 48 + (idx >> 2) * 16 + g * 4 + (idx & 3);
        const int ro = W * 1920 + h * 20;
        const float q2 = QS[W * 1632 + h * 17 + n];
        const uint4* row = (const uint4*)(KVf + ro);
        const uint4 ra = row[0], rb = row[1], rc = row[2], rd = row[3];
        const unsigned kv[16] = {ra.x, ra.y, ra.z, ra.w, rb.x, rb.y, rb.z, rb.w,
                                 rc.x, rc.y, rc.z, rc.w, rd.x, rd.y, rd.z, rd.w};
        float sp[4] = {0.f, 0.f, 0.f, 0.f}, op[4] = {0.f, 0.f, 0.f, 0.f};
#pragma unroll
        for (int tt = 0; tt < 16; ++tt) {
            const f16x2 kv2 = __builtin_bit_cast(f16x2, kv[tt]);
            const float e = __builtin_amdgcn_exp2f(q2 * (float)kv2[0]);
            sp[tt & 3] += e;
            op[tt & 3] = fmaf(e, (float)kv2[1], op[tt & 3]);
        }
        const float s = (sp[0] + sp[1]) + (sp[2] + sp[3]);
        const float o = (op[0] + op[1]) + (op[2] + op[3]);
        KVf[ro + n] = packsplit(o * __builtin_amdgcn_rcpf(s));  // AO over own row
    }
    __syncthreads();

    // ---- out-proj: 3 f-tiles per half, K=96, 2 windows
    f32x4 oc0[3], oc1[3];
#pragma unroll
    for (int c2 = 0; c2 < 3; ++c2) {
        oc0[c2] = (f32x4){0.f, 0.f, 0.f, 0.f};
        oc1[c2] = (f32x4){0.f, 0.f, 0.f, 0.f};
    }
#pragma unroll
    for (int kc = 0; kc < 3; ++kc) {
        const short* whp = WOH + kc * 3072 + n * 32 + g * 8 + hoff;
        const short* wlp = WOL + kc * 3072 + n * 32 + g * 8 + hoff;
        short8 OAH[3], OAL[3];
#pragma unroll
        for (int c2 = 0; c2 < 3; ++c2) OAH[c2] = *(const short8*)(whp + c2 * 512);
#pragma unroll
        for (int c2 = 0; c2 < 3; ++c2) OAL[c2] = *(const short8*)(wlp + c2 * 512);
        unsigned u0[8], u1[8];
#pragma unroll
        for (int j = 0; j < 8; ++j) {
            u0[j] = KVf[(kc * 32 + g * 8 + j) * 20 + n];
            u1[j] = KVf[1920 + (kc * 32 + g * 8 + j) * 20 + n];
        }
        SCHED_PIN();
        short8 bh0, bl0, bh1, bl1;
#pragma unroll
        for (int j = 0; j < 8; ++j) {
            bh0[j] = (short)(u0[j] >> 16); bl0[j] = (short)(u0[j] & 0xffffu);
            bh1[j] = (short)(u1[j] >> 16); bl1[j] = (short)(u1[j] & 0xffffu);
        }
#pragma unroll
        for (int c2 = 0; c2 < 3; ++c2) oc0[c2] = MFMA16(OAH[c2], bh0, oc0[c2], 0, 0, 0);
#pragma unroll
        for (int c2 = 0; c2 < 3; ++c2) oc1[c2] = MFMA16(OAH[c2], bh1, oc1[c2], 0, 0, 0);
#pragma unroll
        for (int c2 = 0; c2 < 3; ++c2) oc0[c2] = MFMA16(OAH[c2], bl0, oc0[c2], 0, 0, 0);
#pragma unroll
        for (int c2 = 0; c2 < 3; ++c2) oc1[c2] = MFMA16(OAH[c2], bl1, oc1[c2], 0, 0, 0);
#pragma unroll
        for (int c2 = 0; c2 < 3; ++c2) oc0[c2] = MFMA16(OAL[c2], bh0, oc0[c2], 0, 0, 0);
#pragma unroll
        for (int c2 = 0; c2 < 3; ++c2) oc1[c2] = MFMA16(OAL[c2], bh1, oc1[c2], 0, 0, 0);
    }

    // ---- bias + direct stores (16 rows x 64B segments), both windows
#pragma unroll
    for (int c2 = 0; c2 < 3; ++c2) {
        const int fb = half * 48 + c2 * 16 + g * 4;
        const float4 ob = *(const float4*)(out_b + fb);
        const float4 vs0 = make_float4(oc0[c2][0] + ob.x, oc0[c2][1] + ob.y,
                                       oc0[c2][2] + ob.z, oc0[c2][3] + ob.w);
        const float4 vs1 = make_float4(oc1[c2][0] + ob.x, oc1[c2][1] + ob.y,
                                       oc1[c2][2] + ob.z, oc1[c2][3] + ob.w);
        *(float4*)(out + (size_t)n * EMB_STRIDE + wl0 * 96 + fb) = vs0;
        *(float4*)(out + (size_t)n * EMB_STRIDE + (wl0 + 1) * 96 + fb) = vs1;
    }
}

extern "C" void kernel_launch(void* const* d_in, const int* in_sizes, int n_in,
                              void* d_out, int out_size, void* d_ws, size_t ws_size,
                              hipStream_t stream) {
    const float* x     = (const float*)d_in[0];
    const float* lin_w = (const float*)d_in[1];
    const float* lin_b = (const float*)d_in[2];
    const float* in_w  = (const float*)d_in[3];
    const float* in_b  = (const float*)d_in[4];
    const float* out_w = (const float*)d_in[5];
    const float* out_b = (const float*)d_in[6];
    float* outp = (float*)d_out;

    unsigned* embp = (unsigned*)d_ws;                       // 25165824 B
    short* WH  = (short*)((char*)d_ws + 25165824);          // 27648 used
    short* WL2 = WH + 32768;
    short* WOH = WH + 65536;                                // 9216 used
    short* WOL = WH + 81920;

    k_patch<<<1088, 256, 0, stream>>>(x, lin_w, lin_b, in_w, out_w,
                                      embp, WH, WL2, WOH, WOL);
    k_msa<<<2048, 128, 0, stream>>>(embp, WH, WL2, WOH, WOL, in_b, out_b, outp);
}

// Round 22
// 65.972 us; speedup vs baseline: 1.0282x; 1.0282x over previous
//
#include <hip/hip_runtime.h>

#define EMB_STRIDE 393216  // 96*64*64 elements per sample

typedef __attribute__((ext_vector_type(8))) short short8;
typedef __attribute__((ext_vector_type(4))) float f32x4;
typedef __attribute__((ext_vector_type(2))) __fp16 f16x2;

#define MFMA16 __builtin_amdgcn_mfma_f32_16x16x32_bf16
#define SCHED_PIN() __builtin_amdgcn_sched_barrier(0)

static __device__ __forceinline__ short bf16h(float v) {
    unsigned u = __builtin_bit_cast(unsigned, v);
    unsigned r = (u + 0x7FFFu + ((u >> 16) & 1u)) >> 16;
    return (short)r;
}
static __device__ __forceinline__ float bf16f(short s) {
    unsigned u = ((unsigned)(unsigned short)s) << 16;
    return __builtin_bit_cast(float, u);
}
// pack value as (hi_bf16 << 16) | lo_bf16 where v ~= hi + lo (lo truncated)
static __device__ __forceinline__ unsigned packsplit(float v) {
    const short h = bf16h(v);
    const float d = v - bf16f(h);
    const unsigned lo = __builtin_bit_cast(unsigned, d) >> 16;
    return ((unsigned)(unsigned short)h << 16) | lo;
}

// ---------------- Kernel 1: patch merge (RAW reshape) + 48->96 linear as MFMA.
// Blocks 0..1023: main patch GEMM, lin_w A-frags loaded INLINE (L2-resident).
// Emb stored as TWO bf16 planes (hi, lo) so k_msa loads short8 with no unpack.
// Blocks 1024..1087: pack in_proj/out_proj into MFMA A-frag hi/lo planes for
// k_msa (64-way parallel; consumed only by the NEXT kernel -> no race).
__global__ __launch_bounds__(256, 3) void k_patch(
    const float* __restrict__ x, const float* __restrict__ lin_w,
    const float* __restrict__ lin_b, const float* __restrict__ in_w,
    const float* __restrict__ out_w,
    short* __restrict__ embH, short* __restrict__ embL,
    short* __restrict__ WH, short* __restrict__ WL2,
    short* __restrict__ WOH, short* __restrict__ WOL) {
    const int bid = blockIdx.x;
    const int tid = threadIdx.x;

    if (bid >= 1024) {
        const int i0 = (bid - 1024) * 256 + tid;
        const int stride = 64 * 256;
        for (int i = i0; i < 27648; i += stride) {
            int j = i & 7, g = (i >> 3) & 3, rest = i >> 5;
            int f = rest % 288, kc = rest / 288;
            float v = in_w[f * 96 + kc * 32 + g * 8 + j];
            short h = bf16h(v);
            WH[i] = h; WL2[i] = bf16h(v - bf16f(h));
        }
        for (int i = i0; i < 9216; i += stride) {
            int j = i & 7, g = (i >> 3) & 3, rest = i >> 5;
            int f = rest % 96, kc = rest / 96;
            float v = out_w[f * 96 + kc * 32 + g * 8 + j];
            short h = bf16h(v);
            WOH[i] = h; WOL[i] = bf16h(v - bf16f(h));
        }
        return;
    }

    const int wave = tid >> 6, lane = tid & 63;
    const int n = bid >> 6;
    const int T = (bid & 63) * 4 + wave;   // 0..255
    const int a = T >> 6, b = (T >> 2) & 15, cc = T & 3;
    const int col16 = lane & 15, grp = lane >> 4;
    const int d = col16 >> 2, g = col16 & 3;

    const int rowoff = (a * 4 + d) * 256 + b * 16 + cc * 4 + g;
    const int gA = (grp >> 1) * 65536 + (grp & 1) * 32768;
    const float* p0 = x + (size_t)n * 196608 + rowoff + gA;

    // ---- B-frags: per-lane gather + bf16 hi/lo split
    float v0[8], v1[8];
#pragma unroll
    for (int j = 0; j < 8; ++j) v0[j] = p0[j * 4096];
    if (grp < 2) {
#pragma unroll
        for (int j = 0; j < 8; ++j) v1[j] = p0[131072 - (grp >> 1) * 65536 + j * 4096];
    }
    SCHED_PIN();
    short8 Bh[2], Bl[2];
#pragma unroll
    for (int j = 0; j < 8; ++j) {
        const short h = bf16h(v0[j]);
        Bh[0][j] = h; Bl[0][j] = bf16h(v0[j] - bf16f(h));
        Bh[1][j] = 0; Bl[1][j] = 0;
    }
    if (grp < 2) {
#pragma unroll
        for (int j = 0; j < 8; ++j) {
            const short h = bf16h(v1[j]);
            Bh[1][j] = h; Bl[1][j] = bf16h(v1[j] - bf16f(h));
        }
    }

    // ---- 6 e-tiles x (2 kc x 3 splits) MFMA; A-frags loaded inline from lin_w.
    f32x4 acc[6];
#pragma unroll
    for (int et = 0; et < 6; ++et) acc[et] = (f32x4){0.f, 0.f, 0.f, 0.f};
#pragma unroll
    for (int kc = 0; kc < 2; ++kc) {
        float wv[6][8];
        const bool valid = (kc == 0) | (grp < 2);
#pragma unroll
        for (int et = 0; et < 6; ++et) {
            const float* wr = lin_w + (et * 16 + col16) * 48 + kc * 32 + grp * 8;
            const float4 wa = valid ? *(const float4*)(wr)     : make_float4(0.f, 0.f, 0.f, 0.f);
            const float4 wb = valid ? *(const float4*)(wr + 4) : make_float4(0.f, 0.f, 0.f, 0.f);
            wv[et][0] = wa.x; wv[et][1] = wa.y; wv[et][2] = wa.z; wv[et][3] = wa.w;
            wv[et][4] = wb.x; wv[et][5] = wb.y; wv[et][6] = wb.z; wv[et][7] = wb.w;
        }
        SCHED_PIN();
        short8 AH[6], AL[6];
#pragma unroll
        for (int et = 0; et < 6; ++et)
#pragma unroll
            for (int j = 0; j < 8; ++j) {
                const short h = bf16h(wv[et][j]);
                AH[et][j] = h;
                AL[et][j] = bf16h(wv[et][j] - bf16f(h));
            }
#pragma unroll
        for (int et = 0; et < 6; ++et) acc[et] = MFMA16(AH[et], Bh[kc], acc[et], 0, 0, 0);
#pragma unroll
        for (int et = 0; et < 6; ++et) acc[et] = MFMA16(AH[et], Bl[kc], acc[et], 0, 0, 0);
#pragma unroll
        for (int et = 0; et < 6; ++et) acc[et] = MFMA16(AL[et], Bh[kc], acc[et], 0, 0, 0);
    }

    // ---- bias + dual-plane store: e = et*16 + grp*4 + r, o = T*16 + col16
    const size_t obase = (size_t)n * EMB_STRIDE + T * 16 + col16;
#pragma unroll
    for (int et = 0; et < 6; ++et) {
        const float4 bv = *(const float4*)(lin_b + et * 16 + grp * 4);
        const float vr[4] = {acc[et][0] + bv.x, acc[et][1] + bv.y,
                             acc[et][2] + bv.z, acc[et][3] + bv.w};
#pragma unroll
        for (int r = 0; r < 4; ++r) {
            const size_t idx = obase + (size_t)(et * 16 + grp * 4 + r) * 4096;
            const short h = bf16h(vr[r]);
            embH[idx] = h;
            embL[idx] = bf16h(vr[r] - bf16f(h));
        }
    }
}

// ---------------- Kernel 2: fused window-MSA (r20/r16 structure).
// Block = 128 threads = 2 half-waves; each WAVE processes BOTH windows.
// B-frags: 24 direct short8 loads from the emb hi/lo planes (zero unpack VALU).
// Softmax via LDS row-staging: packed (k,v) fp16 pairs written to KV[w][h][n]
// (stride 20 u32 -> 80B rows, 16B aligned), then per head-reg FOUR broadcast
// ds_read_b128 replace 16 ds_bpermute.  AO results held in regs, written over
// the same buffer after all reads (wave lockstep, disjoint rows per half).
__global__ __launch_bounds__(128, 2) void k_msa(
    const short* __restrict__ embH, const short* __restrict__ embL,
    const short* __restrict__ WH, const short* __restrict__ WL2,
    const short* __restrict__ WOH, const short* __restrict__ WOL,
    const float* __restrict__ in_b, const float* __restrict__ out_b,
    float* __restrict__ out) {

    __shared__ unsigned KV[2][96 * 20];   // per-window KV then AO, [h][n] stride 20

    const int tid = threadIdx.x;
    const int half = tid >> 6, lane = tid & 63;
    const int wl0 = blockIdx.x * 2;
    const int n = lane & 15, g = lane >> 4;
    const int hoff = half * 1536;

    // ---- B-frags (X^T) for BOTH windows: 24 direct short8 loads, no unpack
    short8 Bh[2][3], Bl[2][3];
#pragma unroll
    for (int w = 0; w < 2; ++w) {
        const short* xh = embH + (size_t)n * EMB_STRIDE + (wl0 + w) * 96;
        const short* xl = embL + (size_t)n * EMB_STRIDE + (wl0 + w) * 96;
#pragma unroll
        for (int kc = 0; kc < 3; ++kc) {
            Bh[w][kc] = *(const short8*)(xh + kc * 32 + g * 8);
            Bl[w][kc] = *(const short8*)(xl + kc * 32 + g * 8);
        }
    }
    SCHED_PIN();

    // ---- QKV: 9 f-tiles per half, K=96, bf16x2, 2 windows
    f32x4 acc0[9], acc1[9];
#pragma unroll
    for (int a = 0; a < 9; ++a) {
        acc0[a] = (f32x4){0.f, 0.f, 0.f, 0.f};
        acc1[a] = (f32x4){0.f, 0.f, 0.f, 0.f};
    }
#pragma unroll
    for (int kc = 0; kc < 3; ++kc) {
        const short* whp = WH  + kc * 9216 + n * 32 + g * 8 + hoff;
        const short* wlp = WL2 + kc * 9216 + n * 32 + g * 8 + hoff;
        short8 AH[9], AL[9];
#pragma unroll
        for (int a = 0; a < 9; ++a)
            AH[a] = *(const short8*)(whp + ((a / 3) * 6 + (a % 3)) * 512);
#pragma unroll
        for (int a = 0; a < 9; ++a)
            AL[a] = *(const short8*)(wlp + ((a / 3) * 6 + (a % 3)) * 512);
        SCHED_PIN();
#pragma unroll
        for (int a = 0; a < 9; ++a) acc0[a] = MFMA16(AH[a], Bh[0][kc], acc0[a], 0, 0, 0);
#pragma unroll
        for (int a = 0; a < 9; ++a) acc1[a] = MFMA16(AH[a], Bh[1][kc], acc1[a], 0, 0, 0);
#pragma unroll
        for (int a = 0; a < 9; ++a) acc0[a] = MFMA16(AH[a], Bl[0][kc], acc0[a], 0, 0, 0);
#pragma unroll
        for (int a = 0; a < 9; ++a) acc1[a] = MFMA16(AH[a], Bl[1][kc], acc1[a], 0, 0, 0);
#pragma unroll
        for (int a = 0; a < 9; ++a) acc0[a] = MFMA16(AL[a], Bh[0][kc], acc0[a], 0, 0, 0);
#pragma unroll
        for (int a = 0; a < 9; ++a) acc1[a] = MFMA16(AL[a], Bh[1][kc], acc1[a], 0, 0, 0);
    }
#pragma unroll
    for (int a = 0; a < 9; ++a) {
        const float4 bv = *(const float4*)(in_b + ((a / 3) * 6 + (a % 3)) * 16 + half * 48 + g * 4);
        acc0[a][0] += bv.x; acc0[a][1] += bv.y; acc0[a][2] += bv.z; acc0[a][3] += bv.w;
        acc1[a][0] += bv.x; acc1[a][1] += bv.y; acc1[a][2] += bv.z; acc1[a][3] += bv.w;
    }

    // ---- phase A: stage packed (k,v) pairs to LDS, both windows
#pragma unroll
    for (int c = 0; c < 3; ++c)
#pragma unroll
        for (int r2 = 0; r2 < 4; ++r2) {
            const int h = half * 48 + c * 16 + g * 4 + r2;
            const f16x2 p0 = __builtin_amdgcn_cvt_pkrtz(acc0[3 + c][r2], acc0[6 + c][r2]);
            const f16x2 p1 = __builtin_amdgcn_cvt_pkrtz(acc1[3 + c][r2], acc1[6 + c][r2]);
            KV[0][h * 20 + n] = __builtin_bit_cast(unsigned, p0);
            KV[1][h * 20 + n] = __builtin_bit_cast(unsigned, p1);
        }

    // ---- phase B: softmax; 4 broadcast b128 row-reads per body
    unsigned ao0[12], ao1[12];
#define ATT_BODY(ACC, W, AOARR)                                                \
    {                                                                          \
        const float q2 = ACC[c][r2] * 1.44269504f;                             \
        const uint4* row = (const uint4*)(&KV[W][(half * 48 + c * 16 + g * 4 + r2) * 20]); \
        const uint4 ra = row[0], rb = row[1], rc = row[2], rd = row[3];        \
        const unsigned kv[16] = {ra.x, ra.y, ra.z, ra.w, rb.x, rb.y, rb.z, rb.w, \
                                 rc.x, rc.y, rc.z, rc.w, rd.x, rd.y, rd.z, rd.w}; \
        float sp[4] = {0.f, 0.f, 0.f, 0.f}, op[4] = {0.f, 0.f, 0.f, 0.f};      \
        _Pragma("unroll")                                                      \
        for (int tt = 0; tt < 16; ++tt) {                                      \
            const f16x2 kv2 = __builtin_bit_cast(f16x2, kv[tt]);               \
            const float e = __builtin_amdgcn_exp2f(q2 * (float)kv2[0]);        \
            sp[tt & 3] += e;                                                   \
            op[tt & 3] = fmaf(e, (float)kv2[1], op[tt & 3]);                   \
        }                                                                      \
        const float s = (sp[0] + sp[1]) + (sp[2] + sp[3]);                     \
        const float o = (op[0] + op[1]) + (op[2] + op[3]);                     \
        AOARR[c * 4 + r2] = packsplit(o * __builtin_amdgcn_rcpf(s));           \
    }
#pragma unroll
    for (int c = 0; c < 3; ++c)
#pragma unroll
        for (int r2 = 0; r2 < 4; ++r2) {
            ATT_BODY(acc0, 0, ao0)
            ATT_BODY(acc1, 1, ao1)
        }

    // ---- phase C: write AO over the KV buffer (all reads of this half done)
#pragma unroll
    for (int c = 0; c < 3; ++c)
#pragma unroll
        for (int r2 = 0; r2 < 4; ++r2) {
            const int h = half * 48 + c * 16 + g * 4 + r2;
            KV[0][h * 20 + n] = ao0[c * 4 + r2];
            KV[1][h * 20 + n] = ao1[c * 4 + r2];
        }
    __syncthreads();

    // ---- out-proj: 3 f-tiles per half, K=96, 2 windows
    f32x4 oc0[3], oc1[3];
#pragma unroll
    for (int c2 = 0; c2 < 3; ++c2) {
        oc0[c2] = (f32x4){0.f, 0.f, 0.f, 0.f};
        oc1[c2] = (f32x4){0.f, 0.f, 0.f, 0.f};
    }
#pragma unroll
    for (int kc = 0; kc < 3; ++kc) {
        const short* whp = WOH + kc * 3072 + n * 32 + g * 8 + hoff;
        const short* wlp = WOL + kc * 3072 + n * 32 + g * 8 + hoff;
        short8 OAH[3], OAL[3];
#pragma unroll
        for (int c2 = 0; c2 < 3; ++c2) OAH[c2] = *(const short8*)(whp + c2 * 512);
#pragma unroll
        for (int c2 = 0; c2 < 3; ++c2) OAL[c2] = *(const short8*)(wlp + c2 * 512);
        unsigned u0[8], u1[8];
#pragma unroll
        for (int j = 0; j < 8; ++j) {
            u0[j] = KV[0][(kc * 32 + g * 8 + j) * 20 + n];
            u1[j] = KV[1][(kc * 32 + g * 8 + j) * 20 + n];
        }
        SCHED_PIN();
        short8 bh0, bl0, bh1, bl1;
#pragma unroll
        for (int j = 0; j < 8; ++j) {
            bh0[j] = (short)(u0[j] >> 16); bl0[j] = (short)(u0[j] & 0xffffu);
            bh1[j] = (short)(u1[j] >> 16); bl1[j] = (short)(u1[j] & 0xffffu);
        }
#pragma unroll
        for (int c2 = 0; c2 < 3; ++c2) oc0[c2] = MFMA16(OAH[c2], bh0, oc0[c2], 0, 0, 0);
#pragma unroll
        for (int c2 = 0; c2 < 3; ++c2) oc1[c2] = MFMA16(OAH[c2], bh1, oc1[c2], 0, 0, 0);
#pragma unroll
        for (int c2 = 0; c2 < 3; ++c2) oc0[c2] = MFMA16(OAH[c2], bl0, oc0[c2], 0, 0, 0);
#pragma unroll
        for (int c2 = 0; c2 < 3; ++c2) oc1[c2] = MFMA16(OAH[c2], bl1, oc1[c2], 0, 0, 0);
#pragma unroll
        for (int c2 = 0; c2 < 3; ++c2) oc0[c2] = MFMA16(OAL[c2], bh0, oc0[c2], 0, 0, 0);
#pragma unroll
        for (int c2 = 0; c2 < 3; ++c2) oc1[c2] = MFMA16(OAL[c2], bh1, oc1[c2], 0, 0, 0);
    }

    // ---- bias + direct stores (16 rows x 64B segments), both windows
#pragma unroll
    for (int c2 = 0; c2 < 3; ++c2) {
        const int fb = half * 48 + c2 * 16 + g * 4;
        const float4 ob = *(const float4*)(out_b + fb);
        const float4 vs0 = make_float4(oc0[c2][0] + ob.x, oc0[c2][1] + ob.y,
                                       oc0[c2][2] + ob.z, oc0[c2][3] + ob.w);
        const float4 vs1 = make_float4(oc1[c2][0] + ob.x, oc1[c2][1] + ob.y,
                                       oc1[c2][2] + ob.z, oc1[c2][3] + ob.w);
        *(float4*)(out + (size_t)n * EMB_STRIDE + wl0 * 96 + fb) = vs0;
        *(float4*)(out + (size_t)n * EMB_STRIDE + (wl0 + 1) * 96 + fb) = vs1;
    }
}

extern "C" void kernel_launch(void* const* d_in, const int* in_sizes, int n_in,
                              void* d_out, int out_size, void* d_ws, size_t ws_size,
                              hipStream_t stream) {
    const float* x     = (const float*)d_in[0];
    const float* lin_w = (const float*)d_in[1];
    const float* lin_b = (const float*)d_in[2];
    const float* in_w  = (const float*)d_in[3];
    const float* in_b  = (const float*)d_in[4];
    const float* out_w = (const float*)d_in[5];
    const float* out_b = (const float*)d_in[6];
    float* outp = (float*)d_out;

    short* embH = (short*)d_ws;                             // 6291456 shorts
    short* embL = embH + 6291456;                           // 6291456 shorts
    short* WH   = embL + 6291456;                           // 27648 used
    short* WL2  = WH + 32768;
    short* WOH  = WH + 65536;                               // 9216 used
    short* WOL  = WH + 81920;

    k_patch<<<1088, 256, 0, stream>>>(x, lin_w, lin_b, in_w, out_w,
                                      embH, embL, WH, WL2, WOH, WOL);
    k_msa<<<2048, 128, 0, stream>>>(embH, embL, WH, WL2, WOH, WOL,
                                    in_b, out_b, outp);
}

// Round 23
// 65.050 us; speedup vs baseline: 1.0428x; 1.0142x over previous
//
#include <hip/hip_runtime.h>

#define EMB_STRIDE 393216  // 96*64*64 elements per sample

typedef __attribute__((ext_vector_type(8))) short short8;
typedef __attribute__((ext_vector_type(4))) float f32x4;
typedef __attribute__((ext_vector_type(2))) __fp16 f16x2;

#define MFMA16 __builtin_amdgcn_mfma_f32_16x16x32_bf16
#define SCHED_PIN() __builtin_amdgcn_sched_barrier(0)

static __device__ __forceinline__ short bf16h(float v) {
    unsigned u = __builtin_bit_cast(unsigned, v);
    unsigned r = (u + 0x7FFFu + ((u >> 16) & 1u)) >> 16;
    return (short)r;
}
static __device__ __forceinline__ float bf16f(short s) {
    unsigned u = ((unsigned)(unsigned short)s) << 16;
    return __builtin_bit_cast(float, u);
}
// pack value as (hi_bf16 << 16) | lo_bf16 where v ~= hi + lo (lo truncated)
static __device__ __forceinline__ unsigned packsplit(float v) {
    const short h = bf16h(v);
    const float d = v - bf16f(h);
    const unsigned lo = __builtin_bit_cast(unsigned, d) >> 16;
    return ((unsigned)(unsigned short)h << 16) | lo;
}

// ---------------- Kernel 1: patch merge (RAW reshape) + 48->96 linear as MFMA.
// Blocks 0..1023: main patch GEMM, lin_w A-frags loaded INLINE (L2-resident).
// Blocks 1024..1087: pack in_proj/out_proj into MFMA A-frag hi/lo planes for
// k_msa, spread over 64 blocks (runs concurrently with patch blocks; consumed
// only by the NEXT kernel -> no intra-kernel dependency).
__global__ __launch_bounds__(256, 3) void k_patch(
    const float* __restrict__ x, const float* __restrict__ lin_w,
    const float* __restrict__ lin_b, const float* __restrict__ in_w,
    const float* __restrict__ out_w, unsigned* __restrict__ embp,
    short* __restrict__ WH, short* __restrict__ WL2,
    short* __restrict__ WOH, short* __restrict__ WOL) {
    const int bid = blockIdx.x;
    const int tid = threadIdx.x;

    if (bid >= 1024) {
        // ---- weight prep for k_msa, 64 blocks x 256 threads grid-stride
        const int i0 = (bid - 1024) * 256 + tid;
        const int stride = 64 * 256;
        for (int i = i0; i < 27648; i += stride) {
            int j = i & 7, g = (i >> 3) & 3, rest = i >> 5;
            int f = rest % 288, kc = rest / 288;
            float v = in_w[f * 96 + kc * 32 + g * 8 + j];
            short h = bf16h(v);
            WH[i] = h; WL2[i] = bf16h(v - bf16f(h));
        }
        for (int i = i0; i < 9216; i += stride) {
            int j = i & 7, g = (i >> 3) & 3, rest = i >> 5;
            int f = rest % 96, kc = rest / 96;
            float v = out_w[f * 96 + kc * 32 + g * 8 + j];
            short h = bf16h(v);
            WOH[i] = h; WOL[i] = bf16h(v - bf16f(h));
        }
        return;
    }

    const int wave = tid >> 6, lane = tid & 63;
    const int n = bid >> 6;
    const int T = (bid & 63) * 4 + wave;   // 0..255
    const int a = T >> 6, b = (T >> 2) & 15, cc = T & 3;
    const int col16 = lane & 15, grp = lane >> 4;
    const int d = col16 >> 2, g = col16 & 3;

    const int rowoff = (a * 4 + d) * 256 + b * 16 + cc * 4 + g;
    const int gA = (grp >> 1) * 65536 + (grp & 1) * 32768;
    const float* p0 = x + (size_t)n * 196608 + rowoff + gA;

    // ---- B-frags: per-lane gather + bf16 hi/lo split
    float v0[8], v1[8];
#pragma unroll
    for (int j = 0; j < 8; ++j) v0[j] = p0[j * 4096];
    if (grp < 2) {
#pragma unroll
        for (int j = 0; j < 8; ++j) v1[j] = p0[131072 - (grp >> 1) * 65536 + j * 4096];
    }
    SCHED_PIN();
    short8 Bh[2], Bl[2];
#pragma unroll
    for (int j = 0; j < 8; ++j) {
        const short h = bf16h(v0[j]);
        Bh[0][j] = h; Bl[0][j] = bf16h(v0[j] - bf16f(h));
        Bh[1][j] = 0; Bl[1][j] = 0;
    }
    if (grp < 2) {
#pragma unroll
        for (int j = 0; j < 8; ++j) {
            const short h = bf16h(v1[j]);
            Bh[1][j] = h; Bl[1][j] = bf16h(v1[j] - bf16f(h));
        }
    }

    // ---- 6 e-tiles x (2 kc x 3 splits) MFMA; A-frags loaded inline from lin_w.
    f32x4 acc[6];
#pragma unroll
    for (int et = 0; et < 6; ++et) acc[et] = (f32x4){0.f, 0.f, 0.f, 0.f};
#pragma unroll
    for (int kc = 0; kc < 2; ++kc) {
        float wv[6][8];
        const bool valid = (kc == 0) | (grp < 2);
#pragma unroll
        for (int et = 0; et < 6; ++et) {
            const float* wr = lin_w + (et * 16 + col16) * 48 + kc * 32 + grp * 8;
            const float4 wa = valid ? *(const float4*)(wr)     : make_float4(0.f, 0.f, 0.f, 0.f);
            const float4 wb = valid ? *(const float4*)(wr + 4) : make_float4(0.f, 0.f, 0.f, 0.f);
            wv[et][0] = wa.x; wv[et][1] = wa.y; wv[et][2] = wa.z; wv[et][3] = wa.w;
            wv[et][4] = wb.x; wv[et][5] = wb.y; wv[et][6] = wb.z; wv[et][7] = wb.w;
        }
        SCHED_PIN();
        short8 AH[6], AL[6];
#pragma unroll
        for (int et = 0; et < 6; ++et)
#pragma unroll
            for (int j = 0; j < 8; ++j) {
                const short h = bf16h(wv[et][j]);
                AH[et][j] = h;
                AL[et][j] = bf16h(wv[et][j] - bf16f(h));
            }
#pragma unroll
        for (int et = 0; et < 6; ++et) acc[et] = MFMA16(AH[et], Bh[kc], acc[et], 0, 0, 0);
#pragma unroll
        for (int et = 0; et < 6; ++et) acc[et] = MFMA16(AH[et], Bl[kc], acc[et], 0, 0, 0);
#pragma unroll
        for (int et = 0; et < 6; ++et) acc[et] = MFMA16(AL[et], Bh[kc], acc[et], 0, 0, 0);
    }

    // ---- bias + packed store: e = et*16 + grp*4 + r, o = T*16 + col16
    unsigned* ebase = embp + (size_t)n * EMB_STRIDE + T * 16 + col16;
#pragma unroll
    for (int et = 0; et < 6; ++et) {
        const float4 bv = *(const float4*)(lin_b + et * 16 + grp * 4);
        const float vr[4] = {acc[et][0] + bv.x, acc[et][1] + bv.y,
                             acc[et][2] + bv.z, acc[et][3] + bv.w};
#pragma unroll
        for (int r = 0; r < 4; ++r)
            ebase[(size_t)(et * 16 + grp * 4 + r) * 4096] = packsplit(vr[r]);
    }
}

// ---------------- Kernel 2: fused window-MSA (best-measured r16/r20 structure).
// Block = 128 threads = 2 half-waves; each WAVE processes BOTH windows.
// Softmax via LDS row-staging: packed (k,v) fp16 pairs written to KV[w][h][n]
// (stride 20 u32 -> 80B rows, 16B aligned), then per head-reg FOUR broadcast
// ds_read_b128 replace 16 ds_bpermute.  AO results held in regs, written over
// the same buffer after all reads (wave lockstep, disjoint rows per half).
__global__ __launch_bounds__(128, 2) void k_msa(
    const unsigned* __restrict__ embp,
    const short* __restrict__ WH, const short* __restrict__ WL2,
    const short* __restrict__ WOH, const short* __restrict__ WOL,
    const float* __restrict__ in_b, const float* __restrict__ out_b,
    float* __restrict__ out) {

    __shared__ unsigned KV[2][96 * 20];   // per-window KV then AO, [h][n] stride 20

    const int tid = threadIdx.x;
    const int half = tid >> 6, lane = tid & 63;
    const int wl0 = blockIdx.x * 2;
    const int n = lane & 15, g = lane >> 4;
    const int hoff = half * 1536;

    // ---- B-frags (X^T) for BOTH windows: 12 uint4 loads in flight
    uint4 ub[12];
#pragma unroll
    for (int w = 0; w < 2; ++w) {
        const unsigned* xrow = embp + (size_t)n * EMB_STRIDE + (wl0 + w) * 96;
#pragma unroll
        for (int kc = 0; kc < 3; ++kc) {
            ub[(w * 3 + kc) * 2]     = *(const uint4*)(xrow + kc * 32 + g * 8);
            ub[(w * 3 + kc) * 2 + 1] = *(const uint4*)(xrow + kc * 32 + g * 8 + 4);
        }
    }
    SCHED_PIN();
    short8 Bh[2][3], Bl[2][3];
#pragma unroll
    for (int w = 0; w < 2; ++w)
#pragma unroll
        for (int kc = 0; kc < 3; ++kc) {
            const uint4 ua0 = ub[(w * 3 + kc) * 2], ua1 = ub[(w * 3 + kc) * 2 + 1];
            const unsigned ua[8] = {ua0.x, ua0.y, ua0.z, ua0.w, ua1.x, ua1.y, ua1.z, ua1.w};
#pragma unroll
            for (int j = 0; j < 8; ++j) {
                Bh[w][kc][j] = (short)(ua[j] >> 16);
                Bl[w][kc][j] = (short)(ua[j] & 0xffffu);
            }
        }

    // ---- QKV: 9 f-tiles per half, K=96, bf16x2, 2 windows
    f32x4 acc0[9], acc1[9];
#pragma unroll
    for (int a = 0; a < 9; ++a) {
        acc0[a] = (f32x4){0.f, 0.f, 0.f, 0.f};
        acc1[a] = (f32x4){0.f, 0.f, 0.f, 0.f};
    }
#pragma unroll
    for (int kc = 0; kc < 3; ++kc) {
        const short* whp = WH  + kc * 9216 + n * 32 + g * 8 + hoff;
        const short* wlp = WL2 + kc * 9216 + n * 32 + g * 8 + hoff;
        short8 AH[9], AL[9];
#pragma unroll
        for (int a = 0; a < 9; ++a)
            AH[a] = *(const short8*)(whp + ((a / 3) * 6 + (a % 3)) * 512);
#pragma unroll
        for (int a = 0; a < 9; ++a)
            AL[a] = *(const short8*)(wlp + ((a / 3) * 6 + (a % 3)) * 512);
        SCHED_PIN();
#pragma unroll
        for (int a = 0; a < 9; ++a) acc0[a] = MFMA16(AH[a], Bh[0][kc], acc0[a], 0, 0, 0);
#pragma unroll
        for (int a = 0; a < 9; ++a) acc1[a] = MFMA16(AH[a], Bh[1][kc], acc1[a], 0, 0, 0);
#pragma unroll
        for (int a = 0; a < 9; ++a) acc0[a] = MFMA16(AH[a], Bl[0][kc], acc0[a], 0, 0, 0);
#pragma unroll
        for (int a = 0; a < 9; ++a) acc1[a] = MFMA16(AH[a], Bl[1][kc], acc1[a], 0, 0, 0);
#pragma unroll
        for (int a = 0; a < 9; ++a) acc0[a] = MFMA16(AL[a], Bh[0][kc], acc0[a], 0, 0, 0);
#pragma unroll
        for (int a = 0; a < 9; ++a) acc1[a] = MFMA16(AL[a], Bh[1][kc], acc1[a], 0, 0, 0);
    }
#pragma unroll
    for (int a = 0; a < 9; ++a) {
        const float4 bv = *(const float4*)(in_b + ((a / 3) * 6 + (a % 3)) * 16 + half * 48 + g * 4);
        acc0[a][0] += bv.x; acc0[a][1] += bv.y; acc0[a][2] += bv.z; acc0[a][3] += bv.w;
        acc1[a][0] += bv.x; acc1[a][1] += bv.y; acc1[a][2] += bv.z; acc1[a][3] += bv.w;
    }

    // ---- phase A: stage packed (k,v) pairs to LDS, both windows
#pragma unroll
    for (int c = 0; c < 3; ++c)
#pragma unroll
        for (int r2 = 0; r2 < 4; ++r2) {
            const int h = half * 48 + c * 16 + g * 4 + r2;
            const f16x2 p0 = __builtin_amdgcn_cvt_pkrtz(acc0[3 + c][r2], acc0[6 + c][r2]);
            const f16x2 p1 = __builtin_amdgcn_cvt_pkrtz(acc1[3 + c][r2], acc1[6 + c][r2]);
            KV[0][h * 20 + n] = __builtin_bit_cast(unsigned, p0);
            KV[1][h * 20 + n] = __builtin_bit_cast(unsigned, p1);
        }

    // ---- phase B: softmax; 4 broadcast b128 row-reads per body
    unsigned ao0[12], ao1[12];
#define ATT_BODY(ACC, W, AOARR)                                                \
    {                                                                          \
        const float q2 = ACC[c][r2] * 1.44269504f;                             \
        const uint4* row = (const uint4*)(&KV[W][(half * 48 + c * 16 + g * 4 + r2) * 20]); \
        const uint4 ra = row[0], rb = row[1], rc = row[2], rd = row[3];        \
        const unsigned kv[16] = {ra.x, ra.y, ra.z, ra.w, rb.x, rb.y, rb.z, rb.w, \
                                 rc.x, rc.y, rc.z, rc.w, rd.x, rd.y, rd.z, rd.w}; \
        float sp[4] = {0.f, 0.f, 0.f, 0.f}, op[4] = {0.f, 0.f, 0.f, 0.f};      \
        _Pragma("unroll")                                                      \
        for (int tt = 0; tt < 16; ++tt) {                                      \
            const f16x2 kv2 = __builtin_bit_cast(f16x2, kv[tt]);               \
            const float e = __builtin_amdgcn_exp2f(q2 * (float)kv2[0]);        \
            sp[tt & 3] += e;                                                   \
            op[tt & 3] = fmaf(e, (float)kv2[1], op[tt & 3]);                   \
        }                                                                      \
        const float s = (sp[0] + sp[1]) + (sp[2] + sp[3]);                     \
        const float o = (op[0] + op[1]) + (op[2] + op[3]);                     \
        AOARR[c * 4 + r2] = packsplit(o * __builtin_amdgcn_rcpf(s));           \
    }
#pragma unroll
    for (int c = 0; c < 3; ++c)
#pragma unroll
        for (int r2 = 0; r2 < 4; ++r2) {
            ATT_BODY(acc0, 0, ao0)
            ATT_BODY(acc1, 1, ao1)
        }

    // ---- phase C: write AO over the KV buffer (all reads of this half done)
#pragma unroll
    for (int c = 0; c < 3; ++c)
#pragma unroll
        for (int r2 = 0; r2 < 4; ++r2) {
            const int h = half * 48 + c * 16 + g * 4 + r2;
            KV[0][h * 20 + n] = ao0[c * 4 + r2];
            KV[1][h * 20 + n] = ao1[c * 4 + r2];
        }
    __syncthreads();

    // ---- out-proj: 3 f-tiles per half, K=96, 2 windows
    f32x4 oc0[3], oc1[3];
#pragma unroll
    for (int c2 = 0; c2 < 3; ++c2) {
        oc0[c2] = (f32x4){0.f, 0.f, 0.f, 0.f};
        oc1[c2] = (f32x4){0.f, 0.f, 0.f, 0.f};
    }
#pragma unroll
    for (int kc = 0; kc < 3; ++kc) {
        const short* whp = WOH + kc * 3072 + n * 32 + g * 8 + hoff;
        const short* wlp = WOL + kc * 3072 + n * 32 + g * 8 + hoff;
        short8 OAH[3], OAL[3];
#pragma unroll
        for (int c2 = 0; c2 < 3; ++c2) OAH[c2] = *(const short8*)(whp + c2 * 512);
#pragma unroll
        for (int c2 = 0; c2 < 3; ++c2) OAL[c2] = *(const short8*)(wlp + c2 * 512);
        unsigned u0[8], u1[8];
#pragma unroll
        for (int j = 0; j < 8; ++j) {
            u0[j] = KV[0][(kc * 32 + g * 8 + j) * 20 + n];
            u1[j] = KV[1][(kc * 32 + g * 8 + j) * 20 + n];
        }
        SCHED_PIN();
        short8 bh0, bl0, bh1, bl1;
#pragma unroll
        for (int j = 0; j < 8; ++j) {
            bh0[j] = (short)(u0[j] >> 16); bl0[j] = (short)(u0[j] & 0xffffu);
            bh1[j] = (short)(u1[j] >> 16); bl1[j] = (short)(u1[j] & 0xffffu);
        }
#pragma unroll
        for (int c2 = 0; c2 < 3; ++c2) oc0[c2] = MFMA16(OAH[c2], bh0, oc0[c2], 0, 0, 0);
#pragma unroll
        for (int c2 = 0; c2 < 3; ++c2) oc1[c2] = MFMA16(OAH[c2], bh1, oc1[c2], 0, 0, 0);
#pragma unroll
        for (int c2 = 0; c2 < 3; ++c2) oc0[c2] = MFMA16(OAH[c2], bl0, oc0[c2], 0, 0, 0);
#pragma unroll
        for (int c2 = 0; c2 < 3; ++c2) oc1[c2] = MFMA16(OAH[c2], bl1, oc1[c2], 0, 0, 0);
#pragma unroll
        for (int c2 = 0; c2 < 3; ++c2) oc0[c2] = MFMA16(OAL[c2], bh0, oc0[c2], 0, 0, 0);
#pragma unroll
        for (int c2 = 0; c2 < 3; ++c2) oc1[c2] = MFMA16(OAL[c2], bh1, oc1[c2], 0, 0, 0);
    }

    // ---- bias + direct stores (16 rows x 64B segments), both windows
#pragma unroll
    for (int c2 = 0; c2 < 3; ++c2) {
        const int fb = half * 48 + c2 * 16 + g * 4;
        const float4 ob = *(const float4*)(out_b + fb);
        const float4 vs0 = make_float4(oc0[c2][0] + ob.x, oc0[c2][1] + ob.y,
                                       oc0[c2][2] + ob.z, oc0[c2][3] + ob.w);
        const float4 vs1 = make_float4(oc1[c2][0] + ob.x, oc1[c2][1] + ob.y,
                                       oc1[c2][2] + ob.z, oc1[c2][3] + ob.w);
        *(float4*)(out + (size_t)n * EMB_STRIDE + wl0 * 96 + fb) = vs0;
        *(float4*)(out + (size_t)n * EMB_STRIDE + (wl0 + 1) * 96 + fb) = vs1;
    }
}

extern "C" void kernel_launch(void* const* d_in, const int* in_sizes, int n_in,
                              void* d_out, int out_size, void* d_ws, size_t ws_size,
                              hipStream_t stream) {
    const float* x     = (const float*)d_in[0];
    const float* lin_w = (const float*)d_in[1];
    const float* lin_b = (const float*)d_in[2];
    const float* in_w  = (const float*)d_in[3];
    const float* in_b  = (const float*)d_in[4];
    const float* out_w = (const float*)d_in[5];
    const float* out_b = (const float*)d_in[6];
    float* outp = (float*)d_out;

    unsigned* embp = (unsigned*)d_ws;                       // 25165824 B
    short* WH  = (short*)((char*)d_ws + 25165824);          // 27648 used
    short* WL2 = WH + 32768;
    short* WOH = WH + 65536;                                // 9216 used
    short* WOL = WH + 81920;

    k_patch<<<1088, 256, 0, stream>>>(x, lin_w, lin_b, in_w, out_w,
                                      embp, WH, WL2, WOH, WOL);
    k_msa<<<2048, 128, 0, stream>>>(embp, WH, WL2, WOH, WOL, in_b, out_b, outp);
}